// Round 8
// baseline (2784.321 us; speedup 1.0000x reference)
//
#include <hip/hip_runtime.h>
#include <hip/hip_fp16.h>

typedef float f32x4 __attribute__((ext_vector_type(4)));
typedef _Float16 f16x8 __attribute__((ext_vector_type(8)));
typedef _Float16 f16x4 __attribute__((ext_vector_type(4)));

// ---------------- LDS byte map ----------------
// Occupancy register-bound at 2 waves/SIMD (r0-r4). r7's fc+L0conv fusion
// spilled (WRITE_SIZE 14MB->165MB). r8 reshapes the fusion for the 128+128
// arch/AGPR budget:
//  - fc mi-split across waves (wave w owns classes w*16..+15, all 98 k-chunks)
//    -> afc 16->8 regs, FCP single partial (argmax 4-way sum gone).
//  - g1h (h1-old) conv moved INTO region3, carried in accL1h (AGPR):
//    L1 inter-barrier section halves; region3 = fc || L0conv || L1hconv,
//    three independent chains over the same nxt rows.
//  - b1 bias cache -> LDS (B1L, 1KB), frees 16 persistent arch regs.
// AGPR: accL0 64 + accL1h 64 = 128 (exact). Arch peak ~105 < 128.
// Layout (54.3 KB, 2 blocks/CU):
//   PL0 @0     [49][264]: h0 ch0..63 (byte 0..127), h1 (128..255)
//   PL1 @12960 same (ping-pong)
//   ST  @25904 [49][528] static gates f16
//   FCP @51792 fc partials; B1L @52816 cx1b+ch1b f32[256]; Z512 @53840 zeros
// Phase A aliasing: XP @25904 (=ST, dies after conv0); XF @PL0; XF2 @PL1.
#define PL0   0
#define PL1   12960
#define STb   25904
#define STSTR 528
#define XPb   25904
#define XFb   0
#define XF2b  12960
#define FCP   51792
#define B1L   52816
#define Z512  53840
#define LDSB  54352

// fast transcendentals: v_exp_f32 (2^x) + v_rcp_f32. Saturation exact at
// +/-inf (rcp(inf)=0). ~1e-7 rel error, drowned by f16 activation storage.
__device__ __forceinline__ float fexp_(float x) {
    return __builtin_amdgcn_exp2f(x * 1.44269504f);
}
__device__ __forceinline__ float sigmoidf_(float v) {
    return __builtin_amdgcn_rcpf(1.0f + fexp_(-v));
}
__device__ __forceinline__ float tanhf_(float v) {
    float e = fexp_(2.0f * v);
    return 1.0f - 2.0f * __builtin_amdgcn_rcpf(e + 1.0f);
}

// shifted-window conv GEMM, weights single f16 (A), acts f16 (B).
// Tap loop deliberately NOT unrolled: keeps the scheduling window small so
// the allocator doesn't hoist 9 taps' worth of loads and spill acc.
template <int NKC, int NMI>
__device__ __forceinline__ void conv_mfma_run(
    const char* __restrict__ SHb, int baseB, int pstr2,
    const int (&kofs)[NKC], int q16,
    const _Float16* __restrict__ g,
    int NMF, int miBase, int miStep,
    const int (&okc)[4], const int (&py0)[4], const int (&px0)[4],
    f32x4 (&acc)[NMI][4], int lane)
{
    #pragma unroll 1
    for (int tap = 0; tap < 9; ++tap) {
        const int dy = tap / 3 - 1, dx = tap % 3 - 1;
        int bb[4];
        #pragma unroll
        for (int n = 0; n < 4; ++n) {
            int py = py0[n] + dy, px = px0[n] + dx;
            bool ok = okc[n] && ((unsigned)py < 7u) && ((unsigned)px < 7u);
            bb[n] = ok ? baseB + (py * 7 + px) * pstr2 : Z512;  // Z512..+512: zeros
        }
        #pragma unroll
        for (int kc = 0; kc < NKC; ++kc) {
            const int kof = kofs[kc] + q16;
            f16x8 B[4];
            #pragma unroll
            for (int n = 0; n < 4; ++n) B[n] = *(const f16x8*)(SHb + bb[n] + kof);
            #pragma unroll
            for (int ii = 0; ii < NMI; ++ii) {
                int frag = (((tap * NKC + kc) * NMF + (miBase + ii * miStep)) << 9) + lane * 8;
                f16x8 Ah = *(const f16x8*)(g + frag);
                #pragma unroll
                for (int n = 0; n < 4; ++n)
                    acc[ii][n] = __builtin_amdgcn_mfma_f32_16x16x32_f16(Ah, B[n], acc[ii][n], 0, 0, 0);
            }
        }
    }
}

// one-hot map conv contribution injected into acc (map one-hot at pixel pv)
__device__ __forceinline__ void inject_onehot(
    f32x4 (&acc)[4][4], const float* __restrict__ wv, int pv,
    const int (&okc)[4], const int (&py0)[4], const int (&px0)[4], int w, int q)
{
    if (pv >= 49) return;                 // EOS / empty map
    int vy = pv / 7, vx = pv % 7;
    #pragma unroll
    for (int n = 0; n < 4; ++n) {
        int dy = vy - py0[n], dx = vx - px0[n];
        if (okc[n] && dy >= -1 && dy <= 1 && dx >= -1 && dx <= 1) {
            int tap = (dy + 1) * 3 + (dx + 1);
            const float* wp = wv + tap * 256 + w * 16 + q * 4;
            #pragma unroll
            for (int g = 0; g < 4; ++g)
                acc[g][n] += *(const f32x4*)(wp + g * 64);
        }
    }
}

extern "C" __global__ __launch_bounds__(256, 2)
void poly_fused(const float* __restrict__ x, const int* __restrict__ firstv,
                const float* __restrict__ b_c0, const float* __restrict__ b_c1,
                const float* __restrict__ cx0b, const float* __restrict__ ch0b,
                const float* __restrict__ cx1b, const float* __restrict__ ch1b,
                const float* __restrict__ fcb,
                const _Float16* __restrict__ c0hi,
                const _Float16* __restrict__ c1hi,
                const _Float16* __restrict__ cshi,
                const _Float16* __restrict__ g0hi,
                const _Float16* __restrict__ g1x, const _Float16* __restrict__ g1h,
                const _Float16* __restrict__ fchi,
                const float* __restrict__ wv1,
                const float* __restrict__ wvp1, const float* __restrict__ wvp2,
                float* __restrict__ out)
{
    extern __shared__ char SHC[];
    float* SHf = (float*)SHC;
    const int tid = threadIdx.x, s = blockIdx.x;
    const int lane = tid & 63, w = tid >> 6;
    const int q = lane >> 4, l15 = lane & 15, q16 = q * 16;

    for (int i = tid; i < LDSB / 4; i += 256) SHf[i] = 0.f;
    __syncthreads();

    // per-lane column geometry (col = n*16 + l15; 49 live pixels)
    int okc[4], py0[4], px0[4];
    #pragma unroll
    for (int n = 0; n < 4; ++n) {
        int col = n * 16 + l15;
        okc[n] = col < 49;
        int p = okc[n] ? col : 0;
        py0[n] = p / 7; px0[n] = p % 7;
    }

    // ============ PHASE A ============
    const float* xs = x + (size_t)s * 12544;
    for (int e = tid; e < 12544; e += 256) {
        int ch = e / 49, p = e - ch * 49;
        *(_Float16*)(SHC + XPb + p * 528 + ch * 2) = (_Float16)xs[e];
    }
    __syncthreads();                       // XP visible

    const int kofs8[8] = {0, 64, 128, 192, 256, 320, 384, 448};
    const int kofs4[4] = {0, 64, 128, 192};
    const int kofs2[2] = {0, 64};

    // conv0: M=128 (8 mfrags; wave owns w*2, w*2+1), K=256; XP -> XF(@PL0)
    {
        f32x4 acc2[2][4];
        #pragma unroll
        for (int ii = 0; ii < 2; ++ii)
            #pragma unroll
            for (int n = 0; n < 4; ++n) acc2[ii][n] = (f32x4){0.f, 0.f, 0.f, 0.f};
        conv_mfma_run<8, 2>(SHC, XPb, 528, kofs8, q16, c0hi,
                            8, w * 2, 1, okc, py0, px0, acc2, lane);
        #pragma unroll
        for (int ii = 0; ii < 2; ++ii) {
            f32x4 bb = *(const f32x4*)(b_c0 + (w * 2 + ii) * 16 + q * 4);
            int chB = ((w * 2 + ii) * 16 + q * 4) * 2;
            #pragma unroll
            for (int n = 0; n < 4; ++n) if (okc[n]) {
                int p = n * 16 + l15;
                f16x4 h;
                #pragma unroll
                for (int r = 0; r < 4; ++r)
                    h[r] = (_Float16)fmaxf(acc2[ii][n][r] + bb[r], 0.f);
                *(f16x4*)(SHC + XFb + p * 264 + chB) = h;
            }
        }
    }
    __syncthreads();                       // XF visible; XP dead

    // conv1: M=128, K=128, XF -> XF2(@PL1)
    {
        f32x4 acc2[2][4];
        #pragma unroll
        for (int ii = 0; ii < 2; ++ii)
            #pragma unroll
            for (int n = 0; n < 4; ++n) acc2[ii][n] = (f32x4){0.f, 0.f, 0.f, 0.f};
        conv_mfma_run<4, 2>(SHC, XFb, 264, kofs4, q16, c1hi,
                            8, w * 2, 1, okc, py0, px0, acc2, lane);
        #pragma unroll
        for (int ii = 0; ii < 2; ++ii) {
            f32x4 bb = *(const f32x4*)(b_c1 + (w * 2 + ii) * 16 + q * 4);
            int chB = ((w * 2 + ii) * 16 + q * 4) * 2;
            #pragma unroll
            for (int n = 0; n < 4; ++n) if (okc[n]) {
                int p = n * 16 + l15;
                f16x4 h;
                #pragma unroll
                for (int r = 0; r < 4; ++r)
                    h[r] = (_Float16)fmaxf(acc2[ii][n][r] + bb[r], 0.f);
                *(f16x4*)(SHC + XF2b + p * 264 + chB) = h;
            }
        }
    }
    __syncthreads();                       // XF2 visible; XF dead

    // static gates: st = conv_cs(x_feat) + (cx0b+ch0b) + v_first window.
    // Writes ST (@XP's dead bytes) — disjoint from XF2 being read.
    // Also: b1L = cx1b+ch1b into LDS; PL0 re-zeroed (h0/h1 old = 0 at t=0).
    const int fv = firstv[s];
    {
        f32x4 acc[4][4];
        #pragma unroll
        for (int g = 0; g < 4; ++g)
            #pragma unroll
            for (int n = 0; n < 4; ++n) acc[g][n] = (f32x4){0.f, 0.f, 0.f, 0.f};
        conv_mfma_run<4, 4>(SHC, XF2b, 264, kofs4, q16, cshi,
                            16, w, 4, okc, py0, px0, acc, lane);
        const int fy = fv / 7, fx = fv % 7;
        #pragma unroll
        for (int g = 0; g < 4; ++g) {
            int m0 = g * 64 + w * 16 + q * 4;
            f32x4 b0 = *(const f32x4*)(cx0b + m0);
            f32x4 bh = *(const f32x4*)(ch0b + m0);
            #pragma unroll
            for (int n = 0; n < 4; ++n) {
                acc[g][n] += b0 + bh;
                int dy = fy - py0[n], dx = fx - px0[n];
                if (okc[n] && dy >= -1 && dy <= 1 && dx >= -1 && dx <= 1) {
                    int tap = (dy + 1) * 3 + (dx + 1);
                    acc[g][n] += *(const f32x4*)(wv1 + tap * 256 + m0);
                }
                if (okc[n]) {
                    int p = n * 16 + l15;
                    f16x4 h;
                    #pragma unroll
                    for (int r = 0; r < 4; ++r) h[r] = (_Float16)acc[g][n][r];
                    *(f16x4*)(SHC + STb + p * STSTR + m0 * 2) = h;
                }
            }
        }
    }
    ((float*)(SHC + B1L))[tid] = cx1b[tid] + ch1b[tid];
    for (int i = tid; i < 12936 / 4; i += 256) SHf[i] = 0.f;   // zero PL0
    __syncthreads();                       // ST + B1L + PL0 zeros visible

    float c0s[4][4], c1s[4][4];
    #pragma unroll
    for (int n = 0; n < 4; ++n)
        #pragma unroll
        for (int r = 0; r < 4; ++r) { c0s[n][r] = 0.f; c1s[n][r] = 0.f; }

    float* outS = out + (size_t)s * 450;
    int p1 = fv, p2 = 49;                  // preds live in registers

    // Carried accumulators (AGPR):
    //   accL0  = ST + conv_g0(h0old)  for step t  (t=0: h0old=0 -> ST only)
    //   accL1h = b1 + conv_g1h(h1old) for step t  (t=0: h1old=0 -> b1 only)
    f32x4 accL0[4][4], accL1h[4][4];
    #pragma unroll
    for (int g = 0; g < 4; ++g) {
        int m0 = g * 64 + w * 16 + q * 4;
        f32x4 bb1 = *(const f32x4*)((const float*)(SHC + B1L) + m0);
        #pragma unroll
        for (int n = 0; n < 4; ++n) {
            int p = okc[n] ? (n * 16 + l15) : 0;
            f16x4 hv = *(const f16x4*)(SHC + STb + p * STSTR + m0 * 2);
            accL0[g][n] = (f32x4){(float)hv[0], (float)hv[1], (float)hv[2], (float)hv[3]};
            accL1h[g][n] = bb1;
        }
    }

    // ============ PHASE B: 9 recurrent steps, 3 barriers each ============
    for (int t = 0; t < 9; ++t) {
        const int nxt = (t & 1) ? PL0 : PL1;
        // ---- one-hot injections (commute with conv already in accL0) ----
        inject_onehot(accL0, wvp1, p1, okc, py0, px0, w, q);
        inject_onehot(accL0, wvp2, p2, okc, py0, px0, w, q);
        {   // L0 LSTM epilogue, write h0new -> nxt h0 (no pending readers)
            int chB = (w * 16 + q * 4) * 2;
            #pragma unroll
            for (int n = 0; n < 4; ++n) if (okc[n]) {
                int p = n * 16 + l15;
                f16x4 h;
                #pragma unroll
                for (int r = 0; r < 4; ++r) {
                    float ig = sigmoidf_(accL0[0][n][r]);
                    float fg = sigmoidf_(accL0[1][n][r]);
                    float gg = tanhf_(accL0[2][n][r]);
                    float og = sigmoidf_(accL0[3][n][r]);
                    float cy = fg * c0s[n][r] + ig * gg;
                    c0s[n][r] = cy;
                    h[r] = (_Float16)(og * tanhf_(cy));
                }
                *(f16x4*)(SHC + nxt + p * 264 + chB) = h;
            }
        }
        __syncthreads();                   // [1] h0new visible
        // ---- L1: accL1h += conv_g1x(h0new); epilogue ----
        conv_mfma_run<2, 4>(SHC, nxt, 264, kofs2, q16, g1x,
                            16, w, 4, okc, py0, px0, accL1h, lane);
        {   // L1 epilogue, write h1new -> nxt h1
            int chB = 128 + (w * 16 + q * 4) * 2;
            #pragma unroll
            for (int n = 0; n < 4; ++n) if (okc[n]) {
                int p = n * 16 + l15;
                f16x4 h;
                #pragma unroll
                for (int r = 0; r < 4; ++r) {
                    float ig = sigmoidf_(accL1h[0][n][r]);
                    float fg = sigmoidf_(accL1h[1][n][r]);
                    float gg = tanhf_(accL1h[2][n][r]);
                    float og = sigmoidf_(accL1h[3][n][r]);
                    float cy = fg * c1s[n][r] + ig * gg;
                    c1s[n][r] = cy;
                    h[r] = (_Float16)(og * tanhf_(cy));
                }
                *(f16x4*)(SHC + nxt + p * 264 + chB) = h;
            }
        }
        __syncthreads();                   // [2] h1new visible
        // ---- region3: fc(t) || L0conv(t+1) || L1hconv(t+1), all over nxt ----
        {
            f32x4 afcA = (f32x4){0.f, 0.f, 0.f, 0.f};
            f32x4 afcB = (f32x4){0.f, 0.f, 0.f, 0.f};
            if (t < 8) {                   // re-init carried accumulators
                #pragma unroll
                for (int g = 0; g < 4; ++g) {
                    int m0 = g * 64 + w * 16 + q * 4;
                    f32x4 bb1 = *(const f32x4*)((const float*)(SHC + B1L) + m0);
                    #pragma unroll
                    for (int n = 0; n < 4; ++n) {
                        int p = okc[n] ? (n * 16 + l15) : 0;
                        f16x4 hv = *(const f16x4*)(SHC + STb + p * STSTR + m0 * 2);
                        accL0[g][n] = (f32x4){(float)hv[0], (float)hv[1], (float)hv[2], (float)hv[3]};
                        accL1h[g][n] = bb1;
                    }
                }
            }
            #pragma unroll 1
            for (int it = 0; it < 9; ++it) {
                // fc slice: wave w owns classes w*16..+15 (mi=w), 11 k-chunks
                int ks = it * 11, ke = (it == 8) ? 98 : ks + 11;
                #pragma unroll 1
                for (int kg = ks; kg < ke; ++kg) {
                    int aB = (l15 == 0) ? (nxt + (kg >> 1) * 264 + 128 + (kg & 1) * 64 + q16) : Z512;
                    f16x8 B = *(const f16x8*)(SHC + aB);
                    f16x8 Ah = *(const f16x8*)(fchi + ((kg * 4 + w) << 9) + lane * 8);
                    if (kg & 1) afcB = __builtin_amdgcn_mfma_f32_16x16x32_f16(Ah, B, afcB, 0, 0, 0);
                    else        afcA = __builtin_amdgcn_mfma_f32_16x16x32_f16(Ah, B, afcA, 0, 0, 0);
                }
                if (t < 8) {               // conv tap `it`: g0 over h0new, g1h over h1new
                    const int dy = it / 3 - 1, dx = it % 3 - 1;
                    int bb[4];
                    #pragma unroll
                    for (int n = 0; n < 4; ++n) {
                        int py = py0[n] + dy, px = px0[n] + dx;
                        bool ok = okc[n] && ((unsigned)py < 7u) && ((unsigned)px < 7u);
                        bb[n] = ok ? nxt + (py * 7 + px) * 264 : Z512;
                    }
                    #pragma unroll
                    for (int kc = 0; kc < 2; ++kc) {
                        const int kof0 = kc * 64 + q16;
                        f16x8 B2[4], B3[4];
                        #pragma unroll
                        for (int n = 0; n < 4; ++n) {
                            B2[n] = *(const f16x8*)(SHC + bb[n] + kof0);
                            B3[n] = *(const f16x8*)(SHC + bb[n] + 128 + kof0);
                        }
                        #pragma unroll
                        for (int ii = 0; ii < 4; ++ii) {
                            int fr = (((it * 2 + kc) * 16 + (w + ii * 4)) << 9) + lane * 8;
                            f16x8 A0 = *(const f16x8*)(g0hi + fr);
                            f16x8 A1 = *(const f16x8*)(g1h + fr);
                            #pragma unroll
                            for (int n = 0; n < 4; ++n) {
                                accL0[ii][n]  = __builtin_amdgcn_mfma_f32_16x16x32_f16(A0, B2[n], accL0[ii][n], 0, 0, 0);
                                accL1h[ii][n] = __builtin_amdgcn_mfma_f32_16x16x32_f16(A1, B3[n], accL1h[ii][n], 0, 0, 0);
                            }
                        }
                    }
                }
            }
            if (l15 == 0) {
                f32x4 afc = afcA + afcB;
                *(f32x4*)(SHC + FCP + w * 64 + q16) = afc;
            }
        }
        __syncthreads();                   // [3] fc partials visible
        // redundant per-wave argmax (identical in all waves)
        {
            const float* fp = (const float*)(SHC + FCP);
            int c = lane;
            float lg = fp[c];
            float v = -3.4e38f;
            if (c < 50) { lg += fcb[c]; v = lg; }
            if (w == 0 && c < 50) outS[t * 50 + c] = lg;
            int idx = c;
            #pragma unroll
            for (int off = 1; off < 64; off <<= 1) {
                float ov = __shfl_xor(v, off, 64);
                int   oi = __shfl_xor(idx, off, 64);
                if (ov > v || (ov == v && oi < idx)) { v = ov; idx = oi; }
            }
            p2 = p1; p1 = idx;
        }
        // no barrier: FCP next written 2 barriers later; nxt(t+1) h-planes'
        // last readers (region3(t)) all completed before bar [3].
    }
}

// ================= weight repack kernels =================
// OIHW conv weights -> A fragments [tap][kc][mi][lane][8], single f16
__global__ void repack_frags_k(const float* __restrict__ w, _Float16* __restrict__ o,
                               int ICS, int KMAX, int NKC, int NMF, int total) {
    int i = blockIdx.x * 256 + threadIdx.x;
    if (i >= total) return;
    int j = i & 7, lane = (i >> 3) & 63;
    int rest = i >> 9;
    int mi = rest % NMF; rest /= NMF;
    int kc = rest % NKC; int tap = rest / NKC;
    int m = mi * 16 + (lane & 15);
    int k = kc * 32 + ((lane >> 4) & 3) * 8 + j;
    float v = (k < KMAX) ? w[((size_t)m * ICS + k) * 9 + tap] : 0.f;
    o[i] = (_Float16)v;
}

// fc weights [50][3136] -> frags [kc 98][mi 4][lane][8], k = p*64+ch, single f16
__global__ void repack_fc_k(const float* __restrict__ fcw, _Float16* __restrict__ o) {
    int i = blockIdx.x * 256 + threadIdx.x;
    if (i >= 200704) return;
    int j = i & 7, lane = (i >> 3) & 63;
    int rest = i >> 9;
    int mi = rest & 3, kc = rest >> 2;
    int cls = mi * 16 + (lane & 15);
    int k = kc * 32 + ((lane >> 4) & 3) * 8 + j;
    int ch = k & 63, p = k >> 6;
    float v = (cls < 50) ? fcw[(size_t)cls * 3136 + ch * 49 + p] : 0.f;
    o[i] = (_Float16)v;
}

// one-hot conv tables: wv[tap][m] = cx0w[m, ic, tap]
__global__ void repack_wv_k(const float* __restrict__ cx0w, float* __restrict__ o, int ic) {
    int i = blockIdx.x * 256 + threadIdx.x;
    if (i >= 2304) return;
    int tap = i / 256, m = i % 256;
    o[i] = cx0w[((size_t)m * 131 + ic) * 9 + tap];
}

extern "C" void kernel_launch(void* const* d_in, const int* in_sizes, int n_in,
                              void* d_out, int out_size, void* d_ws, size_t ws_size,
                              hipStream_t stream)
{
    const float* x     = (const float*)d_in[0];
    const int*   fv    = (const int*)  d_in[1];
    const float* c0w   = (const float*)d_in[2];
    const float* c0b   = (const float*)d_in[3];
    const float* c1w   = (const float*)d_in[4];
    const float* c1b   = (const float*)d_in[5];
    const float* cx0w  = (const float*)d_in[6];
    const float* cx0b  = (const float*)d_in[7];
    const float* ch0w  = (const float*)d_in[8];
    const float* ch0b  = (const float*)d_in[9];
    const float* cx1w  = (const float*)d_in[10];
    const float* cx1b  = (const float*)d_in[11];
    const float* ch1w  = (const float*)d_in[12];
    const float* ch1b  = (const float*)d_in[13];
    const float* fcw   = (const float*)d_in[14];
    const float* fcb   = (const float*)d_in[15];
    float* out = (float*)d_out;
    const int n = in_sizes[0] / 12544;

    _Float16* h = (_Float16*)d_ws;
    _Float16* g0hi = h;                  // 147456 (ch0, NKC=2, NMF=16)
    _Float16* g1x  = g0hi + 147456;      // 147456 (cx1, NKC=2)
    _Float16* g1h  = g1x + 147456;       // 147456 (ch1, NKC=2)
    _Float16* c0hi = g1h + 147456;       // 294912
    _Float16* c1hi = c0hi + 294912;      // 147456
    _Float16* cshi = c1hi + 147456;      // 294912
    _Float16* fchi = cshi + 294912;      // 200704
    float*    wv1  = (float*)(fchi + 200704);   // 2304 f32 each
    float*    wvp1 = wv1 + 2304;
    float*    wvp2 = wvp1 + 2304;

    repack_frags_k<<<(147456 + 255) / 256, 256, 0, stream>>>(ch0w, g0hi, 64, 64, 2, 16, 147456);
    repack_frags_k<<<(147456 + 255) / 256, 256, 0, stream>>>(cx1w, g1x, 64, 64, 2, 16, 147456);
    repack_frags_k<<<(147456 + 255) / 256, 256, 0, stream>>>(ch1w, g1h, 64, 64, 2, 16, 147456);
    repack_frags_k<<<(294912 + 255) / 256, 256, 0, stream>>>(c0w, c0hi, 256, 256, 8, 8, 294912);
    repack_frags_k<<<(147456 + 255) / 256, 256, 0, stream>>>(c1w, c1hi, 128, 128, 4, 8, 147456);
    repack_frags_k<<<(294912 + 255) / 256, 256, 0, stream>>>(cx0w, cshi, 131, 128, 4, 16, 294912);
    repack_fc_k   <<<(200704 + 255) / 256, 256, 0, stream>>>(fcw, fchi);
    repack_wv_k   <<<(2304 + 255) / 256, 256, 0, stream>>>(cx0w, wv1, 130);
    repack_wv_k   <<<(2304 + 255) / 256, 256, 0, stream>>>(cx0w, wvp1, 129);
    repack_wv_k   <<<(2304 + 255) / 256, 256, 0, stream>>>(cx0w, wvp2, 128);

    (void)hipFuncSetAttribute((const void*)poly_fused,
                              hipFuncAttributeMaxDynamicSharedMemorySize, LDSB);
    poly_fused<<<n, 256, LDSB, stream>>>(x, fv, c0b, c1b, cx0b, ch0b, cx1b, ch1b, fcb,
                                         c0hi, c1hi, cshi,
                                         g0hi, g1x, g1h, fchi,
                                         wv1, wvp1, wvp2, out);
}

// Round 9
// 2718.992 us; speedup vs baseline: 1.0240x; 1.0240x over previous
//
#include <hip/hip_runtime.h>
#include <hip/hip_fp16.h>

typedef float f32x4 __attribute__((ext_vector_type(4)));
typedef _Float16 f16x8 __attribute__((ext_vector_type(8)));
typedef _Float16 f16x4 __attribute__((ext_vector_type(4)));

// ---------------- LDS byte map ----------------
// Register model (r0-r8): (256,2) = 128 arch + 128 AGPR per wave, 2 waves/
// SIMD, occupancy fixed. ONE carried 64-reg accumulator fits; two don't:
//   r7 (fc+L0conv fused, afc[4]=16):       spill 165 MB -> 2467 us (best)
//   r8 (+accL1h carried, 128 AGPR exact):  spill 350 MB -> 2784 us
// r9 = r7 structure with region3 pressure cut by ~24 arch regs:
//   - fc mi-split (wave w owns class-frag w, all 98 k-chunks): afc 16->8,
//     FCP single partial, argmax 4-way sum gone  [verified in r8]
//   - b1 bias cache -> LDS B1L (frees 16 persistent arch regs) [r8]
//   - accL0 (64) is the ONLY carried accumulator; L1 back to local-acc
//     two-conv mid-section [r6/r7].
// Layout (54.3 KB, 2 blocks/CU):
//   PL0 @0     [49][264]: h0 ch0..63 (byte 0..127), h1 (128..255)
//   PL1 @12960 same (ping-pong)
//   ST  @25904 [49][528] static gates f16
//   FCP @51792 fc partials; B1L @52816 cx1b+ch1b f32[256]; Z512 @53840 zeros
// Phase A aliasing: XP @25904 (=ST, dies after conv0); XF @PL0; XF2 @PL1.
#define PL0   0
#define PL1   12960
#define STb   25904
#define STSTR 528
#define XPb   25904
#define XFb   0
#define XF2b  12960
#define FCP   51792
#define B1L   52816
#define Z512  53840
#define LDSB  54352

// fast transcendentals: v_exp_f32 (2^x) + v_rcp_f32. Saturation exact at
// +/-inf (rcp(inf)=0). ~1e-7 rel error, drowned by f16 activation storage.
__device__ __forceinline__ float fexp_(float x) {
    return __builtin_amdgcn_exp2f(x * 1.44269504f);
}
__device__ __forceinline__ float sigmoidf_(float v) {
    return __builtin_amdgcn_rcpf(1.0f + fexp_(-v));
}
__device__ __forceinline__ float tanhf_(float v) {
    float e = fexp_(2.0f * v);
    return 1.0f - 2.0f * __builtin_amdgcn_rcpf(e + 1.0f);
}

// shifted-window conv GEMM, weights single f16 (A), acts f16 (B).
// Tap loop deliberately NOT unrolled: keeps the scheduling window small so
// the allocator doesn't hoist 9 taps' worth of loads and spill acc.
template <int NKC, int NMI>
__device__ __forceinline__ void conv_mfma_run(
    const char* __restrict__ SHb, int baseB, int pstr2,
    const int (&kofs)[NKC], int q16,
    const _Float16* __restrict__ g,
    int NMF, int miBase, int miStep,
    const int (&okc)[4], const int (&py0)[4], const int (&px0)[4],
    f32x4 (&acc)[NMI][4], int lane)
{
    #pragma unroll 1
    for (int tap = 0; tap < 9; ++tap) {
        const int dy = tap / 3 - 1, dx = tap % 3 - 1;
        int bb[4];
        #pragma unroll
        for (int n = 0; n < 4; ++n) {
            int py = py0[n] + dy, px = px0[n] + dx;
            bool ok = okc[n] && ((unsigned)py < 7u) && ((unsigned)px < 7u);
            bb[n] = ok ? baseB + (py * 7 + px) * pstr2 : Z512;  // Z512..+512: zeros
        }
        #pragma unroll
        for (int kc = 0; kc < NKC; ++kc) {
            const int kof = kofs[kc] + q16;
            f16x8 B[4];
            #pragma unroll
            for (int n = 0; n < 4; ++n) B[n] = *(const f16x8*)(SHb + bb[n] + kof);
            #pragma unroll
            for (int ii = 0; ii < NMI; ++ii) {
                int frag = (((tap * NKC + kc) * NMF + (miBase + ii * miStep)) << 9) + lane * 8;
                f16x8 Ah = *(const f16x8*)(g + frag);
                #pragma unroll
                for (int n = 0; n < 4; ++n)
                    acc[ii][n] = __builtin_amdgcn_mfma_f32_16x16x32_f16(Ah, B[n], acc[ii][n], 0, 0, 0);
            }
        }
    }
}

// one-hot map conv contribution injected into acc (map one-hot at pixel pv)
__device__ __forceinline__ void inject_onehot(
    f32x4 (&acc)[4][4], const float* __restrict__ wv, int pv,
    const int (&okc)[4], const int (&py0)[4], const int (&px0)[4], int w, int q)
{
    if (pv >= 49) return;                 // EOS / empty map
    int vy = pv / 7, vx = pv % 7;
    #pragma unroll
    for (int n = 0; n < 4; ++n) {
        int dy = vy - py0[n], dx = vx - px0[n];
        if (okc[n] && dy >= -1 && dy <= 1 && dx >= -1 && dx <= 1) {
            int tap = (dy + 1) * 3 + (dx + 1);
            const float* wp = wv + tap * 256 + w * 16 + q * 4;
            #pragma unroll
            for (int g = 0; g < 4; ++g)
                acc[g][n] += *(const f32x4*)(wp + g * 64);
        }
    }
}

extern "C" __global__ __launch_bounds__(256, 2)
void poly_fused(const float* __restrict__ x, const int* __restrict__ firstv,
                const float* __restrict__ b_c0, const float* __restrict__ b_c1,
                const float* __restrict__ cx0b, const float* __restrict__ ch0b,
                const float* __restrict__ cx1b, const float* __restrict__ ch1b,
                const float* __restrict__ fcb,
                const _Float16* __restrict__ c0hi,
                const _Float16* __restrict__ c1hi,
                const _Float16* __restrict__ cshi,
                const _Float16* __restrict__ g0hi,
                const _Float16* __restrict__ g1x, const _Float16* __restrict__ g1h,
                const _Float16* __restrict__ fchi,
                const float* __restrict__ wv1,
                const float* __restrict__ wvp1, const float* __restrict__ wvp2,
                float* __restrict__ out)
{
    extern __shared__ char SHC[];
    float* SHf = (float*)SHC;
    const int tid = threadIdx.x, s = blockIdx.x;
    const int lane = tid & 63, w = tid >> 6;
    const int q = lane >> 4, l15 = lane & 15, q16 = q * 16;

    for (int i = tid; i < LDSB / 4; i += 256) SHf[i] = 0.f;
    __syncthreads();

    // per-lane column geometry (col = n*16 + l15; 49 live pixels)
    int okc[4], py0[4], px0[4];
    #pragma unroll
    for (int n = 0; n < 4; ++n) {
        int col = n * 16 + l15;
        okc[n] = col < 49;
        int p = okc[n] ? col : 0;
        py0[n] = p / 7; px0[n] = p % 7;
    }

    // ============ PHASE A ============
    const float* xs = x + (size_t)s * 12544;
    for (int e = tid; e < 12544; e += 256) {
        int ch = e / 49, p = e - ch * 49;
        *(_Float16*)(SHC + XPb + p * 528 + ch * 2) = (_Float16)xs[e];
    }
    __syncthreads();                       // XP visible

    const int kofs8[8] = {0, 64, 128, 192, 256, 320, 384, 448};
    const int kofs4[4] = {0, 64, 128, 192};
    const int kofs2[2] = {0, 64};
    const int kofs2h[2] = {128, 192};

    // conv0: M=128 (8 mfrags; wave owns w*2, w*2+1), K=256; XP -> XF(@PL0)
    {
        f32x4 acc2[2][4];
        #pragma unroll
        for (int ii = 0; ii < 2; ++ii)
            #pragma unroll
            for (int n = 0; n < 4; ++n) acc2[ii][n] = (f32x4){0.f, 0.f, 0.f, 0.f};
        conv_mfma_run<8, 2>(SHC, XPb, 528, kofs8, q16, c0hi,
                            8, w * 2, 1, okc, py0, px0, acc2, lane);
        #pragma unroll
        for (int ii = 0; ii < 2; ++ii) {
            f32x4 bb = *(const f32x4*)(b_c0 + (w * 2 + ii) * 16 + q * 4);
            int chB = ((w * 2 + ii) * 16 + q * 4) * 2;
            #pragma unroll
            for (int n = 0; n < 4; ++n) if (okc[n]) {
                int p = n * 16 + l15;
                f16x4 h;
                #pragma unroll
                for (int r = 0; r < 4; ++r)
                    h[r] = (_Float16)fmaxf(acc2[ii][n][r] + bb[r], 0.f);
                *(f16x4*)(SHC + XFb + p * 264 + chB) = h;
            }
        }
    }
    __syncthreads();                       // XF visible; XP dead

    // conv1: M=128, K=128, XF -> XF2(@PL1)
    {
        f32x4 acc2[2][4];
        #pragma unroll
        for (int ii = 0; ii < 2; ++ii)
            #pragma unroll
            for (int n = 0; n < 4; ++n) acc2[ii][n] = (f32x4){0.f, 0.f, 0.f, 0.f};
        conv_mfma_run<4, 2>(SHC, XFb, 264, kofs4, q16, c1hi,
                            8, w * 2, 1, okc, py0, px0, acc2, lane);
        #pragma unroll
        for (int ii = 0; ii < 2; ++ii) {
            f32x4 bb = *(const f32x4*)(b_c1 + (w * 2 + ii) * 16 + q * 4);
            int chB = ((w * 2 + ii) * 16 + q * 4) * 2;
            #pragma unroll
            for (int n = 0; n < 4; ++n) if (okc[n]) {
                int p = n * 16 + l15;
                f16x4 h;
                #pragma unroll
                for (int r = 0; r < 4; ++r)
                    h[r] = (_Float16)fmaxf(acc2[ii][n][r] + bb[r], 0.f);
                *(f16x4*)(SHC + XF2b + p * 264 + chB) = h;
            }
        }
    }
    __syncthreads();                       // XF2 visible; XF dead

    // static gates: st = conv_cs(x_feat) + (cx0b+ch0b) + v_first window.
    // Writes ST (@XP's dead bytes) — disjoint from XF2 being read.
    // Also: b1L = cx1b+ch1b into LDS; PL0 re-zeroed (h0/h1 old = 0 at t=0).
    const int fv = firstv[s];
    {
        f32x4 acc[4][4];
        #pragma unroll
        for (int g = 0; g < 4; ++g)
            #pragma unroll
            for (int n = 0; n < 4; ++n) acc[g][n] = (f32x4){0.f, 0.f, 0.f, 0.f};
        conv_mfma_run<4, 4>(SHC, XF2b, 264, kofs4, q16, cshi,
                            16, w, 4, okc, py0, px0, acc, lane);
        const int fy = fv / 7, fx = fv % 7;
        #pragma unroll
        for (int g = 0; g < 4; ++g) {
            int m0 = g * 64 + w * 16 + q * 4;
            f32x4 b0 = *(const f32x4*)(cx0b + m0);
            f32x4 bh = *(const f32x4*)(ch0b + m0);
            #pragma unroll
            for (int n = 0; n < 4; ++n) {
                acc[g][n] += b0 + bh;
                int dy = fy - py0[n], dx = fx - px0[n];
                if (okc[n] && dy >= -1 && dy <= 1 && dx >= -1 && dx <= 1) {
                    int tap = (dy + 1) * 3 + (dx + 1);
                    acc[g][n] += *(const f32x4*)(wv1 + tap * 256 + m0);
                }
                if (okc[n]) {
                    int p = n * 16 + l15;
                    f16x4 h;
                    #pragma unroll
                    for (int r = 0; r < 4; ++r) h[r] = (_Float16)acc[g][n][r];
                    *(f16x4*)(SHC + STb + p * STSTR + m0 * 2) = h;
                }
            }
        }
    }
    ((float*)(SHC + B1L))[tid] = cx1b[tid] + ch1b[tid];
    for (int i = tid; i < 12936 / 4; i += 256) SHf[i] = 0.f;   // zero PL0
    __syncthreads();                       // ST + B1L + PL0 zeros visible

    float c0s[4][4], c1s[4][4];
    #pragma unroll
    for (int n = 0; n < 4; ++n)
        #pragma unroll
        for (int r = 0; r < 4; ++r) { c0s[n][r] = 0.f; c1s[n][r] = 0.f; }

    float* outS = out + (size_t)s * 450;
    int p1 = fv, p2 = 49;                  // preds live in registers

    // accL0: ST + conv_g0(h0old) for step t, carried in AGPR (the ONLY
    // carried accumulator). t=0: h0old=0 -> ST only (conv skipped).
    f32x4 accL0[4][4];
    #pragma unroll
    for (int g = 0; g < 4; ++g) {
        int m0 = g * 64 + w * 16 + q * 4;
        #pragma unroll
        for (int n = 0; n < 4; ++n) {
            int p = okc[n] ? (n * 16 + l15) : 0;
            f16x4 hv = *(const f16x4*)(SHC + STb + p * STSTR + m0 * 2);
            accL0[g][n] = (f32x4){(float)hv[0], (float)hv[1], (float)hv[2], (float)hv[3]};
        }
    }

    // ============ PHASE B: 9 recurrent steps, 3 barriers each ============
    for (int t = 0; t < 9; ++t) {
        const int cur = (t & 1) ? PL1 : PL0;
        const int nxt = (t & 1) ? PL0 : PL1;
        // ---- one-hot injections (commute with conv already in accL0) ----
        inject_onehot(accL0, wvp1, p1, okc, py0, px0, w, q);
        inject_onehot(accL0, wvp2, p2, okc, py0, px0, w, q);
        {   // L0 LSTM epilogue, write h0new -> nxt h0 (no pending readers)
            int chB = (w * 16 + q * 4) * 2;
            #pragma unroll
            for (int n = 0; n < 4; ++n) if (okc[n]) {
                int p = n * 16 + l15;
                f16x4 h;
                #pragma unroll
                for (int r = 0; r < 4; ++r) {
                    float ig = sigmoidf_(accL0[0][n][r]);
                    float fg = sigmoidf_(accL0[1][n][r]);
                    float gg = tanhf_(accL0[2][n][r]);
                    float og = sigmoidf_(accL0[3][n][r]);
                    float cy = fg * c0s[n][r] + ig * gg;
                    c0s[n][r] = cy;
                    h[r] = (_Float16)(og * tanhf_(cy));
                }
                *(f16x4*)(SHC + nxt + p * 264 + chB) = h;
            }
        }
        __syncthreads();                   // [1] h0new visible
        // ---- L1 gates: K = [h0new (nxt) | h1old (cur)], local acc ----
        {
            f32x4 acc[4][4];
            #pragma unroll
            for (int g = 0; g < 4; ++g) {
                int m0 = g * 64 + w * 16 + q * 4;
                f32x4 bb1 = *(const f32x4*)((const float*)(SHC + B1L) + m0);
                #pragma unroll
                for (int n = 0; n < 4; ++n) acc[g][n] = bb1;
            }
            conv_mfma_run<2, 4>(SHC, nxt, 264, kofs2, q16, g1x,
                                16, w, 4, okc, py0, px0, acc, lane);
            conv_mfma_run<2, 4>(SHC, cur, 264, kofs2h, q16, g1h,
                                16, w, 4, okc, py0, px0, acc, lane);
            // L1 epilogue, write h1new -> nxt h1
            int chB = 128 + (w * 16 + q * 4) * 2;
            #pragma unroll
            for (int n = 0; n < 4; ++n) if (okc[n]) {
                int p = n * 16 + l15;
                f16x4 h;
                #pragma unroll
                for (int r = 0; r < 4; ++r) {
                    float ig = sigmoidf_(acc[0][n][r]);
                    float fg = sigmoidf_(acc[1][n][r]);
                    float gg = tanhf_(acc[2][n][r]);
                    float og = sigmoidf_(acc[3][n][r]);
                    float cy = fg * c1s[n][r] + ig * gg;
                    c1s[n][r] = cy;
                    h[r] = (_Float16)(og * tanhf_(cy));
                }
                *(f16x4*)(SHC + nxt + p * 264 + chB) = h;
            }
        }
        __syncthreads();                   // [2] h1new visible
        // ---- region3: fc(t) fused with L0conv(t+1), both over nxt ----
        {
            f32x4 afcA = (f32x4){0.f, 0.f, 0.f, 0.f};
            f32x4 afcB = (f32x4){0.f, 0.f, 0.f, 0.f};
            if (t < 8) {                   // re-init accL0 = ST for step t+1
                #pragma unroll
                for (int g = 0; g < 4; ++g) {
                    int m0 = g * 64 + w * 16 + q * 4;
                    #pragma unroll
                    for (int n = 0; n < 4; ++n) {
                        int p = okc[n] ? (n * 16 + l15) : 0;
                        f16x4 hv = *(const f16x4*)(SHC + STb + p * STSTR + m0 * 2);
                        accL0[g][n] = (f32x4){(float)hv[0], (float)hv[1], (float)hv[2], (float)hv[3]};
                    }
                }
            }
            #pragma unroll 1
            for (int it = 0; it < 9; ++it) {
                // fc slice: wave w owns class-frag w (classes w*16..+15), 11 k-chunks
                int ks = it * 11, ke = (it == 8) ? 98 : ks + 11;
                #pragma unroll 1
                for (int kg = ks; kg < ke; ++kg) {
                    int aB = (l15 == 0) ? (nxt + (kg >> 1) * 264 + 128 + (kg & 1) * 64 + q16) : Z512;
                    f16x8 B = *(const f16x8*)(SHC + aB);
                    f16x8 Ah = *(const f16x8*)(fchi + ((kg * 4 + w) << 9) + lane * 8);
                    if (kg & 1) afcB = __builtin_amdgcn_mfma_f32_16x16x32_f16(Ah, B, afcB, 0, 0, 0);
                    else        afcA = __builtin_amdgcn_mfma_f32_16x16x32_f16(Ah, B, afcA, 0, 0, 0);
                }
                if (t < 8) {
                    // L0conv(t+1) tap `it` over h0new (nxt), g0 weights
                    const int dy = it / 3 - 1, dx = it % 3 - 1;
                    int bb[4];
                    #pragma unroll
                    for (int n = 0; n < 4; ++n) {
                        int py = py0[n] + dy, px = px0[n] + dx;
                        bool ok = okc[n] && ((unsigned)py < 7u) && ((unsigned)px < 7u);
                        bb[n] = ok ? nxt + (py * 7 + px) * 264 : Z512;
                    }
                    #pragma unroll
                    for (int kc = 0; kc < 2; ++kc) {
                        const int kof = kc * 64 + q16;
                        f16x8 B2[4];
                        #pragma unroll
                        for (int n = 0; n < 4; ++n) B2[n] = *(const f16x8*)(SHC + bb[n] + kof);
                        #pragma unroll
                        for (int ii = 0; ii < 4; ++ii) {
                            int fr = (((it * 2 + kc) * 16 + (w + ii * 4)) << 9) + lane * 8;
                            f16x8 A0 = *(const f16x8*)(g0hi + fr);
                            #pragma unroll
                            for (int n = 0; n < 4; ++n)
                                accL0[ii][n] = __builtin_amdgcn_mfma_f32_16x16x32_f16(A0, B2[n], accL0[ii][n], 0, 0, 0);
                        }
                    }
                }
            }
            if (l15 == 0) {
                f32x4 afc = afcA + afcB;
                *(f32x4*)(SHC + FCP + w * 64 + q16) = afc;
            }
        }
        __syncthreads();                   // [3] fc partials visible
        // redundant per-wave argmax (identical in all waves)
        {
            const float* fp = (const float*)(SHC + FCP);
            int c = lane;
            float lg = fp[c];
            float v = -3.4e38f;
            if (c < 50) { lg += fcb[c]; v = lg; }
            if (w == 0 && c < 50) outS[t * 50 + c] = lg;
            int idx = c;
            #pragma unroll
            for (int off = 1; off < 64; off <<= 1) {
                float ov = __shfl_xor(v, off, 64);
                int   oi = __shfl_xor(idx, off, 64);
                if (ov > v || (ov == v && oi < idx)) { v = ov; idx = oi; }
            }
            p2 = p1; p1 = idx;
        }
        // no barrier: FCP next written 2 barriers later; nxt(t+1)'s last
        // readers (region3(t)) completed before bar [3].
    }
}

// ================= weight repack kernels =================
// OIHW conv weights -> A fragments [tap][kc][mi][lane][8], single f16
__global__ void repack_frags_k(const float* __restrict__ w, _Float16* __restrict__ o,
                               int ICS, int KMAX, int NKC, int NMF, int total) {
    int i = blockIdx.x * 256 + threadIdx.x;
    if (i >= total) return;
    int j = i & 7, lane = (i >> 3) & 63;
    int rest = i >> 9;
    int mi = rest % NMF; rest /= NMF;
    int kc = rest % NKC; int tap = rest / NKC;
    int m = mi * 16 + (lane & 15);
    int k = kc * 32 + ((lane >> 4) & 3) * 8 + j;
    float v = (k < KMAX) ? w[((size_t)m * ICS + k) * 9 + tap] : 0.f;
    o[i] = (_Float16)v;
}

// fc weights [50][3136] -> frags [kc 98][mi 4][lane][8], k = p*64+ch, single f16
__global__ void repack_fc_k(const float* __restrict__ fcw, _Float16* __restrict__ o) {
    int i = blockIdx.x * 256 + threadIdx.x;
    if (i >= 200704) return;
    int j = i & 7, lane = (i >> 3) & 63;
    int rest = i >> 9;
    int mi = rest & 3, kc = rest >> 2;
    int cls = mi * 16 + (lane & 15);
    int k = kc * 32 + ((lane >> 4) & 3) * 8 + j;
    int ch = k & 63, p = k >> 6;
    float v = (cls < 50) ? fcw[(size_t)cls * 3136 + ch * 49 + p] : 0.f;
    o[i] = (_Float16)v;
}

// one-hot conv tables: wv[tap][m] = cx0w[m, ic, tap]
__global__ void repack_wv_k(const float* __restrict__ cx0w, float* __restrict__ o, int ic) {
    int i = blockIdx.x * 256 + threadIdx.x;
    if (i >= 2304) return;
    int tap = i / 256, m = i % 256;
    o[i] = cx0w[((size_t)m * 131 + ic) * 9 + tap];
}

extern "C" void kernel_launch(void* const* d_in, const int* in_sizes, int n_in,
                              void* d_out, int out_size, void* d_ws, size_t ws_size,
                              hipStream_t stream)
{
    const float* x     = (const float*)d_in[0];
    const int*   fv    = (const int*)  d_in[1];
    const float* c0w   = (const float*)d_in[2];
    const float* c0b   = (const float*)d_in[3];
    const float* c1w   = (const float*)d_in[4];
    const float* c1b   = (const float*)d_in[5];
    const float* cx0w  = (const float*)d_in[6];
    const float* cx0b  = (const float*)d_in[7];
    const float* ch0w  = (const float*)d_in[8];
    const float* ch0b  = (const float*)d_in[9];
    const float* cx1w  = (const float*)d_in[10];
    const float* cx1b  = (const float*)d_in[11];
    const float* ch1w  = (const float*)d_in[12];
    const float* ch1b  = (const float*)d_in[13];
    const float* fcw   = (const float*)d_in[14];
    const float* fcb   = (const float*)d_in[15];
    float* out = (float*)d_out;
    const int n = in_sizes[0] / 12544;

    _Float16* h = (_Float16*)d_ws;
    _Float16* g0hi = h;                  // 147456 (ch0, NKC=2, NMF=16)
    _Float16* g1x  = g0hi + 147456;      // 147456 (cx1, NKC=2)
    _Float16* g1h  = g1x + 147456;       // 147456 (ch1, NKC=2)
    _Float16* c0hi = g1h + 147456;       // 294912
    _Float16* c1hi = c0hi + 294912;      // 147456
    _Float16* cshi = c1hi + 147456;      // 294912
    _Float16* fchi = cshi + 294912;      // 200704
    float*    wv1  = (float*)(fchi + 200704);   // 2304 f32 each
    float*    wvp1 = wv1 + 2304;
    float*    wvp2 = wvp1 + 2304;

    repack_frags_k<<<(147456 + 255) / 256, 256, 0, stream>>>(ch0w, g0hi, 64, 64, 2, 16, 147456);
    repack_frags_k<<<(147456 + 255) / 256, 256, 0, stream>>>(cx1w, g1x, 64, 64, 2, 16, 147456);
    repack_frags_k<<<(147456 + 255) / 256, 256, 0, stream>>>(ch1w, g1h, 64, 64, 2, 16, 147456);
    repack_frags_k<<<(294912 + 255) / 256, 256, 0, stream>>>(c0w, c0hi, 256, 256, 8, 8, 294912);
    repack_frags_k<<<(147456 + 255) / 256, 256, 0, stream>>>(c1w, c1hi, 128, 128, 4, 8, 147456);
    repack_frags_k<<<(294912 + 255) / 256, 256, 0, stream>>>(cx0w, cshi, 131, 128, 4, 16, 294912);
    repack_fc_k   <<<(200704 + 255) / 256, 256, 0, stream>>>(fcw, fchi);
    repack_wv_k   <<<(2304 + 255) / 256, 256, 0, stream>>>(cx0w, wv1, 130);
    repack_wv_k   <<<(2304 + 255) / 256, 256, 0, stream>>>(cx0w, wvp1, 129);
    repack_wv_k   <<<(2304 + 255) / 256, 256, 0, stream>>>(cx0w, wvp2, 128);

    (void)hipFuncSetAttribute((const void*)poly_fused,
                              hipFuncAttributeMaxDynamicSharedMemorySize, LDSB);
    poly_fused<<<n, 256, LDSB, stream>>>(x, fv, c0b, c1b, cx0b, ch0b, cx1b, ch1b, fcb,
                                         c0hi, c1hi, cshi,
                                         g0hi, g1x, g1h, fchi,
                                         wv1, wvp1, wvp2, out);
}

// Round 10
// 2329.354 us; speedup vs baseline: 1.1953x; 1.1673x over previous
//
#include <hip/hip_runtime.h>
#include <hip/hip_fp16.h>

typedef float f32x4 __attribute__((ext_vector_type(4)));
typedef _Float16 f16x8 __attribute__((ext_vector_type(8)));
typedef _Float16 f16x4 __attribute__((ext_vector_type(4)));

// ---------------- LDS byte map ----------------
// Register model (r0-r9): (256,2) = 128 arch + 128 AGPR, 2 waves/SIMD fixed.
// r7 (fc K-split + fc||L0conv fusion) = 2467 us best, but spills ~300 B/thd
// (165 MB writes). r9 showed the spill is invariant to shaving transient
// regs, and that mi-split fc kills ILP (98x1 dep-chained MFMAs vs 25x4).
// r10 = r7 exactly, minus 32 LIVE-ACROSS regs at the region3 pressure peak:
//   - c1s LSTM cell state -> LDS C1S [16][260] f32 (scalar lane-contiguous,
//     conflict-free; exact f32 round-trip). Was 16 regs live through r1/r3.
//   - b1 bias cache -> LDS B1L (16 regs freed; proven r9).
// fc stays K-split (afc[4], 4-way FCP partials); accL0 stays the only
// carried AGPR accumulator.
// Layout (70992 B, 2 blocks/CU = 142 KB <= 160 KB):
//   PL0 @0     [49][264]: h0 ch0..63 (byte 0..127), h1 (128..255)
//   PL1 @12960 same (ping-pong)
//   ST  @25904 [49][528] static gates f16 (ends 51776)
//   FCP @51792 fc partials (1 KB); B1L @52816 cx1b+ch1b f32[256] (1 KB)
//   C1S @53840 c1 cell state f32 [16][260] (16640 B)
//   Z512 @70480 zeros (OOB fallback)
// Phase A aliasing: XP @25904 (=ST, dies after conv0); XF @PL0; XF2 @PL1.
#define PL0   0
#define PL1   12960
#define STb   25904
#define STSTR 528
#define XPb   25904
#define XFb   0
#define XF2b  12960
#define FCP   51792
#define B1L   52816
#define C1S   53840
#define Z512  70480
#define LDSB  70992

// fast transcendentals: v_exp_f32 (2^x) + v_rcp_f32. Saturation exact at
// +/-inf (rcp(inf)=0). ~1e-7 rel error, drowned by f16 activation storage.
__device__ __forceinline__ float fexp_(float x) {
    return __builtin_amdgcn_exp2f(x * 1.44269504f);
}
__device__ __forceinline__ float sigmoidf_(float v) {
    return __builtin_amdgcn_rcpf(1.0f + fexp_(-v));
}
__device__ __forceinline__ float tanhf_(float v) {
    float e = fexp_(2.0f * v);
    return 1.0f - 2.0f * __builtin_amdgcn_rcpf(e + 1.0f);
}

// shifted-window conv GEMM, weights single f16 (A), acts f16 (B).
// Tap loop deliberately NOT unrolled: keeps the scheduling window small so
// the allocator doesn't hoist 9 taps' worth of loads and spill acc.
template <int NKC, int NMI>
__device__ __forceinline__ void conv_mfma_run(
    const char* __restrict__ SHb, int baseB, int pstr2,
    const int (&kofs)[NKC], int q16,
    const _Float16* __restrict__ g,
    int NMF, int miBase, int miStep,
    const int (&okc)[4], const int (&py0)[4], const int (&px0)[4],
    f32x4 (&acc)[NMI][4], int lane)
{
    #pragma unroll 1
    for (int tap = 0; tap < 9; ++tap) {
        const int dy = tap / 3 - 1, dx = tap % 3 - 1;
        int bb[4];
        #pragma unroll
        for (int n = 0; n < 4; ++n) {
            int py = py0[n] + dy, px = px0[n] + dx;
            bool ok = okc[n] && ((unsigned)py < 7u) && ((unsigned)px < 7u);
            bb[n] = ok ? baseB + (py * 7 + px) * pstr2 : Z512;  // Z512..+512: zeros
        }
        #pragma unroll
        for (int kc = 0; kc < NKC; ++kc) {
            const int kof = kofs[kc] + q16;
            f16x8 B[4];
            #pragma unroll
            for (int n = 0; n < 4; ++n) B[n] = *(const f16x8*)(SHb + bb[n] + kof);
            #pragma unroll
            for (int ii = 0; ii < NMI; ++ii) {
                int frag = (((tap * NKC + kc) * NMF + (miBase + ii * miStep)) << 9) + lane * 8;
                f16x8 Ah = *(const f16x8*)(g + frag);
                #pragma unroll
                for (int n = 0; n < 4; ++n)
                    acc[ii][n] = __builtin_amdgcn_mfma_f32_16x16x32_f16(Ah, B[n], acc[ii][n], 0, 0, 0);
            }
        }
    }
}

// one-hot map conv contribution injected into acc (map one-hot at pixel pv)
__device__ __forceinline__ void inject_onehot(
    f32x4 (&acc)[4][4], const float* __restrict__ wv, int pv,
    const int (&okc)[4], const int (&py0)[4], const int (&px0)[4], int w, int q)
{
    if (pv >= 49) return;                 // EOS / empty map
    int vy = pv / 7, vx = pv % 7;
    #pragma unroll
    for (int n = 0; n < 4; ++n) {
        int dy = vy - py0[n], dx = vx - px0[n];
        if (okc[n] && dy >= -1 && dy <= 1 && dx >= -1 && dx <= 1) {
            int tap = (dy + 1) * 3 + (dx + 1);
            const float* wp = wv + tap * 256 + w * 16 + q * 4;
            #pragma unroll
            for (int g = 0; g < 4; ++g)
                acc[g][n] += *(const f32x4*)(wp + g * 64);
        }
    }
}

extern "C" __global__ __launch_bounds__(256, 2)
void poly_fused(const float* __restrict__ x, const int* __restrict__ firstv,
                const float* __restrict__ b_c0, const float* __restrict__ b_c1,
                const float* __restrict__ cx0b, const float* __restrict__ ch0b,
                const float* __restrict__ cx1b, const float* __restrict__ ch1b,
                const float* __restrict__ fcb,
                const _Float16* __restrict__ c0hi,
                const _Float16* __restrict__ c1hi,
                const _Float16* __restrict__ cshi,
                const _Float16* __restrict__ g0hi,
                const _Float16* __restrict__ g1x, const _Float16* __restrict__ g1h,
                const _Float16* __restrict__ fchi,
                const float* __restrict__ wv1,
                const float* __restrict__ wvp1, const float* __restrict__ wvp2,
                float* __restrict__ out)
{
    extern __shared__ char SHC[];
    float* SHf = (float*)SHC;
    const int tid = threadIdx.x, s = blockIdx.x;
    const int lane = tid & 63, w = tid >> 6;
    const int q = lane >> 4, l15 = lane & 15, q16 = q * 16;

    for (int i = tid; i < LDSB / 4; i += 256) SHf[i] = 0.f;
    __syncthreads();

    // per-lane column geometry (col = n*16 + l15; 49 live pixels)
    int okc[4], py0[4], px0[4];
    #pragma unroll
    for (int n = 0; n < 4; ++n) {
        int col = n * 16 + l15;
        okc[n] = col < 49;
        int p = okc[n] ? col : 0;
        py0[n] = p / 7; px0[n] = p % 7;
    }

    // ============ PHASE A ============
    const float* xs = x + (size_t)s * 12544;
    for (int e = tid; e < 12544; e += 256) {
        int ch = e / 49, p = e - ch * 49;
        *(_Float16*)(SHC + XPb + p * 528 + ch * 2) = (_Float16)xs[e];
    }
    __syncthreads();                       // XP visible

    const int kofs8[8] = {0, 64, 128, 192, 256, 320, 384, 448};
    const int kofs4[4] = {0, 64, 128, 192};
    const int kofs2[2] = {0, 64};
    const int kofs2h[2] = {128, 192};

    // conv0: M=128 (8 mfrags; wave owns w*2, w*2+1), K=256; XP -> XF(@PL0)
    {
        f32x4 acc2[2][4];
        #pragma unroll
        for (int ii = 0; ii < 2; ++ii)
            #pragma unroll
            for (int n = 0; n < 4; ++n) acc2[ii][n] = (f32x4){0.f, 0.f, 0.f, 0.f};
        conv_mfma_run<8, 2>(SHC, XPb, 528, kofs8, q16, c0hi,
                            8, w * 2, 1, okc, py0, px0, acc2, lane);
        #pragma unroll
        for (int ii = 0; ii < 2; ++ii) {
            f32x4 bb = *(const f32x4*)(b_c0 + (w * 2 + ii) * 16 + q * 4);
            int chB = ((w * 2 + ii) * 16 + q * 4) * 2;
            #pragma unroll
            for (int n = 0; n < 4; ++n) if (okc[n]) {
                int p = n * 16 + l15;
                f16x4 h;
                #pragma unroll
                for (int r = 0; r < 4; ++r)
                    h[r] = (_Float16)fmaxf(acc2[ii][n][r] + bb[r], 0.f);
                *(f16x4*)(SHC + XFb + p * 264 + chB) = h;
            }
        }
    }
    __syncthreads();                       // XF visible; XP dead

    // conv1: M=128, K=128, XF -> XF2(@PL1)
    {
        f32x4 acc2[2][4];
        #pragma unroll
        for (int ii = 0; ii < 2; ++ii)
            #pragma unroll
            for (int n = 0; n < 4; ++n) acc2[ii][n] = (f32x4){0.f, 0.f, 0.f, 0.f};
        conv_mfma_run<4, 2>(SHC, XFb, 264, kofs4, q16, c1hi,
                            8, w * 2, 1, okc, py0, px0, acc2, lane);
        #pragma unroll
        for (int ii = 0; ii < 2; ++ii) {
            f32x4 bb = *(const f32x4*)(b_c1 + (w * 2 + ii) * 16 + q * 4);
            int chB = ((w * 2 + ii) * 16 + q * 4) * 2;
            #pragma unroll
            for (int n = 0; n < 4; ++n) if (okc[n]) {
                int p = n * 16 + l15;
                f16x4 h;
                #pragma unroll
                for (int r = 0; r < 4; ++r)
                    h[r] = (_Float16)fmaxf(acc2[ii][n][r] + bb[r], 0.f);
                *(f16x4*)(SHC + XF2b + p * 264 + chB) = h;
            }
        }
    }
    __syncthreads();                       // XF2 visible; XF dead

    // static gates: st = conv_cs(x_feat) + (cx0b+ch0b) + v_first window.
    // Writes ST (@XP's dead bytes) — disjoint from XF2 being read.
    // Also: b1L = cx1b+ch1b into LDS; PL0 re-zeroed (h0/h1 old = 0 at t=0).
    const int fv = firstv[s];
    {
        f32x4 acc[4][4];
        #pragma unroll
        for (int g = 0; g < 4; ++g)
            #pragma unroll
            for (int n = 0; n < 4; ++n) acc[g][n] = (f32x4){0.f, 0.f, 0.f, 0.f};
        conv_mfma_run<4, 4>(SHC, XF2b, 264, kofs4, q16, cshi,
                            16, w, 4, okc, py0, px0, acc, lane);
        const int fy = fv / 7, fx = fv % 7;
        #pragma unroll
        for (int g = 0; g < 4; ++g) {
            int m0 = g * 64 + w * 16 + q * 4;
            f32x4 b0 = *(const f32x4*)(cx0b + m0);
            f32x4 bh = *(const f32x4*)(ch0b + m0);
            #pragma unroll
            for (int n = 0; n < 4; ++n) {
                acc[g][n] += b0 + bh;
                int dy = fy - py0[n], dx = fx - px0[n];
                if (okc[n] && dy >= -1 && dy <= 1 && dx >= -1 && dx <= 1) {
                    int tap = (dy + 1) * 3 + (dx + 1);
                    acc[g][n] += *(const f32x4*)(wv1 + tap * 256 + m0);
                }
                if (okc[n]) {
                    int p = n * 16 + l15;
                    f16x4 h;
                    #pragma unroll
                    for (int r = 0; r < 4; ++r) h[r] = (_Float16)acc[g][n][r];
                    *(f16x4*)(SHC + STb + p * STSTR + m0 * 2) = h;
                }
            }
        }
    }
    ((float*)(SHC + B1L))[tid] = cx1b[tid] + ch1b[tid];
    for (int i = tid; i < 12936 / 4; i += 256) SHf[i] = 0.f;   // zero PL0
    __syncthreads();                       // ST + B1L + PL0 zeros visible

    float c0s[4][4];
    #pragma unroll
    for (int n = 0; n < 4; ++n)
        #pragma unroll
        for (int r = 0; r < 4; ++r) c0s[n][r] = 0.f;
    // c1 cell state lives in LDS C1S [16][260] f32, zeroed above.
    float* C1Sf = (float*)(SHC + C1S);

    float* outS = out + (size_t)s * 450;
    int p1 = fv, p2 = 49;                  // preds live in registers

    // accL0: ST + conv_g0(h0old) for step t, carried in AGPR (the ONLY
    // carried accumulator). t=0: h0old=0 -> ST only (conv skipped).
    f32x4 accL0[4][4];
    #pragma unroll
    for (int g = 0; g < 4; ++g) {
        int m0 = g * 64 + w * 16 + q * 4;
        #pragma unroll
        for (int n = 0; n < 4; ++n) {
            int p = okc[n] ? (n * 16 + l15) : 0;
            f16x4 hv = *(const f16x4*)(SHC + STb + p * STSTR + m0 * 2);
            accL0[g][n] = (f32x4){(float)hv[0], (float)hv[1], (float)hv[2], (float)hv[3]};
        }
    }

    // ============ PHASE B: 9 recurrent steps, 3 barriers each ============
    for (int t = 0; t < 9; ++t) {
        const int cur = (t & 1) ? PL1 : PL0;
        const int nxt = (t & 1) ? PL0 : PL1;
        // ---- one-hot injections (commute with conv already in accL0) ----
        inject_onehot(accL0, wvp1, p1, okc, py0, px0, w, q);
        inject_onehot(accL0, wvp2, p2, okc, py0, px0, w, q);
        {   // L0 LSTM epilogue, write h0new -> nxt h0 (no pending readers)
            int chB = (w * 16 + q * 4) * 2;
            #pragma unroll
            for (int n = 0; n < 4; ++n) if (okc[n]) {
                int p = n * 16 + l15;
                f16x4 h;
                #pragma unroll
                for (int r = 0; r < 4; ++r) {
                    float ig = sigmoidf_(accL0[0][n][r]);
                    float fg = sigmoidf_(accL0[1][n][r]);
                    float gg = tanhf_(accL0[2][n][r]);
                    float og = sigmoidf_(accL0[3][n][r]);
                    float cy = fg * c0s[n][r] + ig * gg;
                    c0s[n][r] = cy;
                    h[r] = (_Float16)(og * tanhf_(cy));
                }
                *(f16x4*)(SHC + nxt + p * 264 + chB) = h;
            }
        }
        __syncthreads();                   // [1] h0new visible
        // ---- L1 gates: K = [h0new (nxt) | h1old (cur)], local acc ----
        {
            f32x4 acc[4][4];
            #pragma unroll
            for (int g = 0; g < 4; ++g) {
                int m0 = g * 64 + w * 16 + q * 4;
                f32x4 bb1 = *(const f32x4*)((const float*)(SHC + B1L) + m0);
                #pragma unroll
                for (int n = 0; n < 4; ++n) acc[g][n] = bb1;
            }
            conv_mfma_run<2, 4>(SHC, nxt, 264, kofs2, q16, g1x,
                                16, w, 4, okc, py0, px0, acc, lane);
            conv_mfma_run<2, 4>(SHC, cur, 264, kofs2h, q16, g1h,
                                16, w, 4, okc, py0, px0, acc, lane);
            // L1 epilogue, write h1new -> nxt h1; c1 state via LDS (exact f32)
            int chB = 128 + (w * 16 + q * 4) * 2;
            #pragma unroll
            for (int n = 0; n < 4; ++n) if (okc[n]) {
                int p = n * 16 + l15;
                f16x4 h;
                #pragma unroll
                for (int r = 0; r < 4; ++r) {
                    float ig = sigmoidf_(acc[0][n][r]);
                    float fg = sigmoidf_(acc[1][n][r]);
                    float gg = tanhf_(acc[2][n][r]);
                    float og = sigmoidf_(acc[3][n][r]);
                    int ci = (n * 4 + r) * 260 + tid;
                    float cy = fg * C1Sf[ci] + ig * gg;
                    C1Sf[ci] = cy;
                    h[r] = (_Float16)(og * tanhf_(cy));
                }
                *(f16x4*)(SHC + nxt + p * 264 + chB) = h;
            }
        }
        __syncthreads();                   // [2] h1new visible
        // ---- region3: fc(t) fused with L0conv(t+1), both over nxt ----
        {
            f32x4 afc[4];
            #pragma unroll
            for (int mi = 0; mi < 4; ++mi) afc[mi] = (f32x4){0.f, 0.f, 0.f, 0.f};
            if (t < 8) {                   // re-init accL0 = ST for step t+1
                #pragma unroll
                for (int g = 0; g < 4; ++g) {
                    int m0 = g * 64 + w * 16 + q * 4;
                    #pragma unroll
                    for (int n = 0; n < 4; ++n) {
                        int p = okc[n] ? (n * 16 + l15) : 0;
                        f16x4 hv = *(const f16x4*)(SHC + STb + p * STSTR + m0 * 2);
                        accL0[g][n] = (f32x4){(float)hv[0], (float)hv[1], (float)hv[2], (float)hv[3]};
                    }
                }
            }
            int kc0 = w * 25;
            int kcN = (w < 3) ? 25 : 23;
            #pragma unroll 1
            for (int it = 0; it < 9; ++it) {
                // fc slice: ~3 k-chunks (K-split: 4 independent MFMAs per B)
                int ks = it * 3, ke = ks + 3; if (ke > kcN) ke = kcN;
                #pragma unroll 1
                for (int kc = ks; kc < ke; ++kc) {
                    int kg = kc0 + kc;
                    int aB = (l15 == 0) ? (nxt + (kg >> 1) * 264 + 128 + (kg & 1) * 64 + q16) : Z512;
                    f16x8 B = *(const f16x8*)(SHC + aB);
                    #pragma unroll
                    for (int mi = 0; mi < 4; ++mi) {
                        int frag = ((kg * 4 + mi) << 9) + lane * 8;
                        f16x8 Ah = *(const f16x8*)(fchi + frag);
                        afc[mi] = __builtin_amdgcn_mfma_f32_16x16x32_f16(Ah, B, afc[mi], 0, 0, 0);
                    }
                }
                if (t < 8) {
                    // L0conv(t+1) tap `it` over h0new (nxt), g0 weights
                    const int dy = it / 3 - 1, dx = it % 3 - 1;
                    int bb[4];
                    #pragma unroll
                    for (int n = 0; n < 4; ++n) {
                        int py = py0[n] + dy, px = px0[n] + dx;
                        bool ok = okc[n] && ((unsigned)py < 7u) && ((unsigned)px < 7u);
                        bb[n] = ok ? nxt + (py * 7 + px) * 264 : Z512;
                    }
                    #pragma unroll
                    for (int kc = 0; kc < 2; ++kc) {
                        const int kof = kc * 64 + q16;
                        f16x8 B2[4];
                        #pragma unroll
                        for (int n = 0; n < 4; ++n) B2[n] = *(const f16x8*)(SHC + bb[n] + kof);
                        #pragma unroll
                        for (int ii = 0; ii < 4; ++ii) {
                            int fr = (((it * 2 + kc) * 16 + (w + ii * 4)) << 9) + lane * 8;
                            f16x8 A0 = *(const f16x8*)(g0hi + fr);
                            #pragma unroll
                            for (int n = 0; n < 4; ++n)
                                accL0[ii][n] = __builtin_amdgcn_mfma_f32_16x16x32_f16(A0, B2[n], accL0[ii][n], 0, 0, 0);
                        }
                    }
                }
            }
            if (l15 == 0) {
                #pragma unroll
                for (int mi = 0; mi < 4; ++mi)
                    *(f32x4*)(SHC + FCP + w * 256 + mi * 64 + q16) = afc[mi];
            }
        }
        __syncthreads();                   // [3] fc partials visible
        // redundant per-wave argmax (identical in all waves)
        {
            const float* fp = (const float*)(SHC + FCP);
            int c = lane;
            float lg = fp[c] + fp[64 + c] + fp[128 + c] + fp[192 + c];
            float v = -3.4e38f;
            if (c < 50) { lg += fcb[c]; v = lg; }
            if (w == 0 && c < 50) outS[t * 50 + c] = lg;
            int idx = c;
            #pragma unroll
            for (int off = 1; off < 64; off <<= 1) {
                float ov = __shfl_xor(v, off, 64);
                int   oi = __shfl_xor(idx, off, 64);
                if (ov > v || (ov == v && oi < idx)) { v = ov; idx = oi; }
            }
            p2 = p1; p1 = idx;
        }
        // no barrier: FCP next written 2 barriers later; nxt(t+1)'s last
        // readers (region3(t)) completed before bar [3].
    }
}

// ================= weight repack kernels =================
// OIHW conv weights -> A fragments [tap][kc][mi][lane][8], single f16
__global__ void repack_frags_k(const float* __restrict__ w, _Float16* __restrict__ o,
                               int ICS, int KMAX, int NKC, int NMF, int total) {
    int i = blockIdx.x * 256 + threadIdx.x;
    if (i >= total) return;
    int j = i & 7, lane = (i >> 3) & 63;
    int rest = i >> 9;
    int mi = rest % NMF; rest /= NMF;
    int kc = rest % NKC; int tap = rest / NKC;
    int m = mi * 16 + (lane & 15);
    int k = kc * 32 + ((lane >> 4) & 3) * 8 + j;
    float v = (k < KMAX) ? w[((size_t)m * ICS + k) * 9 + tap] : 0.f;
    o[i] = (_Float16)v;
}

// fc weights [50][3136] -> frags [kc 98][mi 4][lane][8], k = p*64+ch, single f16
__global__ void repack_fc_k(const float* __restrict__ fcw, _Float16* __restrict__ o) {
    int i = blockIdx.x * 256 + threadIdx.x;
    if (i >= 200704) return;
    int j = i & 7, lane = (i >> 3) & 63;
    int rest = i >> 9;
    int mi = rest & 3, kc = rest >> 2;
    int cls = mi * 16 + (lane & 15);
    int k = kc * 32 + ((lane >> 4) & 3) * 8 + j;
    int ch = k & 63, p = k >> 6;
    float v = (cls < 50) ? fcw[(size_t)cls * 3136 + ch * 49 + p] : 0.f;
    o[i] = (_Float16)v;
}

// one-hot conv tables: wv[tap][m] = cx0w[m, ic, tap]
__global__ void repack_wv_k(const float* __restrict__ cx0w, float* __restrict__ o, int ic) {
    int i = blockIdx.x * 256 + threadIdx.x;
    if (i >= 2304) return;
    int tap = i / 256, m = i % 256;
    o[i] = cx0w[((size_t)m * 131 + ic) * 9 + tap];
}

extern "C" void kernel_launch(void* const* d_in, const int* in_sizes, int n_in,
                              void* d_out, int out_size, void* d_ws, size_t ws_size,
                              hipStream_t stream)
{
    const float* x     = (const float*)d_in[0];
    const int*   fv    = (const int*)  d_in[1];
    const float* c0w   = (const float*)d_in[2];
    const float* c0b   = (const float*)d_in[3];
    const float* c1w   = (const float*)d_in[4];
    const float* c1b   = (const float*)d_in[5];
    const float* cx0w  = (const float*)d_in[6];
    const float* cx0b  = (const float*)d_in[7];
    const float* ch0w  = (const float*)d_in[8];
    const float* ch0b  = (const float*)d_in[9];
    const float* cx1w  = (const float*)d_in[10];
    const float* cx1b  = (const float*)d_in[11];
    const float* ch1w  = (const float*)d_in[12];
    const float* ch1b  = (const float*)d_in[13];
    const float* fcw   = (const float*)d_in[14];
    const float* fcb   = (const float*)d_in[15];
    float* out = (float*)d_out;
    const int n = in_sizes[0] / 12544;

    _Float16* h = (_Float16*)d_ws;
    _Float16* g0hi = h;                  // 147456 (ch0, NKC=2, NMF=16)
    _Float16* g1x  = g0hi + 147456;      // 147456 (cx1, NKC=2)
    _Float16* g1h  = g1x + 147456;       // 147456 (ch1, NKC=2)
    _Float16* c0hi = g1h + 147456;       // 294912
    _Float16* c1hi = c0hi + 294912;      // 147456
    _Float16* cshi = c1hi + 147456;      // 294912
    _Float16* fchi = cshi + 294912;      // 200704
    float*    wv1  = (float*)(fchi + 200704);   // 2304 f32 each
    float*    wvp1 = wv1 + 2304;
    float*    wvp2 = wvp1 + 2304;

    repack_frags_k<<<(147456 + 255) / 256, 256, 0, stream>>>(ch0w, g0hi, 64, 64, 2, 16, 147456);
    repack_frags_k<<<(147456 + 255) / 256, 256, 0, stream>>>(cx1w, g1x, 64, 64, 2, 16, 147456);
    repack_frags_k<<<(147456 + 255) / 256, 256, 0, stream>>>(ch1w, g1h, 64, 64, 2, 16, 147456);
    repack_frags_k<<<(294912 + 255) / 256, 256, 0, stream>>>(c0w, c0hi, 256, 256, 8, 8, 294912);
    repack_frags_k<<<(147456 + 255) / 256, 256, 0, stream>>>(c1w, c1hi, 128, 128, 4, 8, 147456);
    repack_frags_k<<<(294912 + 255) / 256, 256, 0, stream>>>(cx0w, cshi, 131, 128, 4, 16, 294912);
    repack_fc_k   <<<(200704 + 255) / 256, 256, 0, stream>>>(fcw, fchi);
    repack_wv_k   <<<(2304 + 255) / 256, 256, 0, stream>>>(cx0w, wv1, 130);
    repack_wv_k   <<<(2304 + 255) / 256, 256, 0, stream>>>(cx0w, wvp1, 129);
    repack_wv_k   <<<(2304 + 255) / 256, 256, 0, stream>>>(cx0w, wvp2, 128);

    (void)hipFuncSetAttribute((const void*)poly_fused,
                              hipFuncAttributeMaxDynamicSharedMemorySize, LDSB);
    poly_fused<<<n, 256, LDSB, stream>>>(x, fv, c0b, c1b, cx0b, ch0b, cx1b, ch1b, fcb,
                                         c0hi, c1hi, cshi,
                                         g0hi, g1x, g1h, fchi,
                                         wv1, wvp1, wvp2, out);
}